// Round 11
// baseline (621.638 us; speedup 1.0000x reference)
//
#include <hip/hip_runtime.h>
#include <float.h>

typedef __attribute__((ext_vector_type(8))) short short8;
typedef __attribute__((ext_vector_type(16))) float f32x16;
typedef unsigned short u16;

#define N_ROWS 65536
#define K_CB   4096
#define D_DIM  256
#define TAU    1.0e-3f
#define RR     8

// old-path tile params (fallback)
#define RB 128
#define KB 128
#define DB 32

// workspace layout (bytes)
#define WS_COUNTER 0
#define WS_ESQ     16
#define WS_IDX     (WS_ESQ + K_CB*4)
#define WS_FLAG    (WS_IDX + N_ROWS*4)
#define WS_PART    (WS_FLAG + N_ROWS*4)
#define NUM_OUT_BLOCKS ((N_ROWS*(D_DIM/4))/256)   // 16384
#define WS_EH      (WS_PART + NUM_OUT_BLOCKS*8)
#define WS_EL      (WS_EH + K_CB*D_DIM*2)
#define WS_NEEDED  (WS_EL + (size_t)K_CB*D_DIM*2)

// ---------- bf16 split helpers (RNE) ----------
__device__ __forceinline__ u16 f2bf(float x) {
  unsigned int u = __float_as_uint(x);
  unsigned int r = (u + 0x7fffu + ((u >> 16) & 1u)) >> 16;
  return (u16)r;
}
__device__ __forceinline__ float bf2f(u16 b) {
  return __uint_as_float((unsigned int)b << 16);
}
// np-exact final combine: fl( fl(zsq+esq) - fl(2*dot) )
__device__ __forceinline__ float np_score(float zsq, float ek, float dot) {
#pragma clang fp contract(off)
  float t1 = zsq + ek;
  float t2 = 2.0f * dot;
  return t1 - t2;
}

// ---------- numpy-emulated pairwise sum of squares ----------
__device__ __forceinline__ float np_sum128_sq(const float* p) {
#pragma clang fp contract(off)
  float r0 = p[0]*p[0], r1 = p[1]*p[1], r2 = p[2]*p[2], r3 = p[3]*p[3];
  float r4 = p[4]*p[4], r5 = p[5]*p[5], r6 = p[6]*p[6], r7 = p[7]*p[7];
  for (int i = 8; i < 128; i += 8) {
    r0 += p[i+0]*p[i+0]; r1 += p[i+1]*p[i+1];
    r2 += p[i+2]*p[i+2]; r3 += p[i+3]*p[i+3];
    r4 += p[i+4]*p[i+4]; r5 += p[i+5]*p[i+5];
    r6 += p[i+6]*p[i+6]; r7 += p[i+7]*p[i+7];
  }
  return ((r0+r1)+(r2+r3))+((r4+r5)+(r6+r7));
}
__device__ __forceinline__ float np_sumsq256(const float* p) {
#pragma clang fp contract(off)
  float a = np_sum128_sq(p);
  float b = np_sum128_sq(p + 128);
  return a + b;
}

__global__ __launch_bounds__(256) void esq_np_kernel(const float* __restrict__ cb,
                                                     float* __restrict__ esq) {
  const int k = blockIdx.x * 256 + threadIdx.x;
  esq[k] = np_sumsq256(cb + (size_t)k * D_DIM);
}

// ---------- codebook split into MFMA-fragment-permuted bf16 hi/lo ----------
// Chunk kc = 32 codes. Element layout within chunk (8192 elems = 16 KB):
//   off = d8*256 + c*8 + j   (d8 = d>>3, c = code&31, j = d&7)
// B-frag ds_read for k-step s, lane l: contiguous 16B at
//   s*1024 + (l>>5)*512 + (l&31)*16  bytes — conflict-free. [R4-proven]
__global__ __launch_bounds__(256) void esplit_perm_kernel(const float* __restrict__ cb,
                                                          u16* __restrict__ ehp,
                                                          u16* __restrict__ elp) {
  const int g  = blockIdx.x * 256 + threadIdx.x;   // K*D/8 threads
  const int k  = g >> 5;
  const int d8 = g & 31;
  const int kc = k >> 5, c = k & 31;
  const float* src = cb + (size_t)k * D_DIM + d8 * 8;
  float4 f0 = *(const float4*)src;
  float4 f1 = *(const float4*)(src + 4);
  float f[8] = {f0.x, f0.y, f0.z, f0.w, f1.x, f1.y, f1.z, f1.w};
  short8 h, lo;
  #pragma unroll
  for (int j = 0; j < 8; ++j) {
    u16 hb = f2bf(f[j]);
    h[j]  = (short)hb;
    lo[j] = (short)f2bf(f[j] - bf2f(hb));
  }
  const size_t off = (size_t)kc * 8192 + (size_t)d8 * 256 + (size_t)c * 8;
  *(short8*)(ehp + off) = h;
  *(short8*)(elp + off) = lo;
}

// ---------------- 32x32x16 split-bf16 MFMA argmin, 64 rows/wave ----------------
// 256 thr = 4 waves, 1 block/CU (launch_bounds(256,1): 1 wave/SIMD, 512-reg
// budget — no spill). Wave owns TWO 32-row A-blocks (hi/lo persistent, 256
// VGPRs): each of the 32 ds_read_b128 per chunk now feeds 6 MFMAs (96/chunk),
// halving per-CU LDS traffic per unit MFMA vs R10 — the measured wall.
// 4 independent acc chains; B staged via global_load_lds (R10-validated).
__global__ __launch_bounds__(256, 1) void mfma_argmin32_kernel(
    const float* __restrict__ z, const u16* __restrict__ ehp,
    const u16* __restrict__ elp, const float* __restrict__ esq,
    int* __restrict__ idx_out, int* __restrict__ flag,
    unsigned int* __restrict__ counter) {
  __shared__ u16 smem[2 * 16384];   // 64 KB
  const int t   = threadIdx.x;
  const int w   = t >> 6;
  const int l   = t & 63;
  const int col = l & 31;
  const int hi  = l >> 5;
  const int rowbase = blockIdx.x * 256 + w * 64;
  const int wbase = w * 1024;       // wave-uniform LDS byte base

  // A fragments: two row-blocks, each split to bf16 hi/lo, 16 k-steps of 16
  short8 ah0[16], al0[16], ah1[16], al1[16];
  #pragma unroll
  for (int rb = 0; rb < 2; ++rb) {
    const float* zr = z + (size_t)(rowbase + rb * 32 + col) * D_DIM + hi * 8;
    #pragma unroll
    for (int s = 0; s < 16; ++s) {
      float4 f0 = *(const float4*)(zr + s * 16);
      float4 f1 = *(const float4*)(zr + s * 16 + 4);
      float f[8] = {f0.x, f0.y, f0.z, f0.w, f1.x, f1.y, f1.z, f1.w};
      short8 h, lo;
      #pragma unroll
      for (int j = 0; j < 8; ++j) {
        u16 hb = f2bf(f[j]);
        h[j]  = (short)hb;
        lo[j] = (short)f2bf(f[j] - bf2f(hb));
      }
      if (rb == 0) { ah0[s] = h; al0[s] = lo; }
      else         { ah1[s] = h; al1[s] = lo; }
    }
  }

  float m1[32], m2[32]; int ic[32];
  #pragma unroll
  for (int j = 0; j < 32; ++j) { m1[j] = FLT_MAX; m2[j] = FLT_MAX; ic[j] = 0; }

  // async global->LDS staging of one chunk (eh 16KB + el 16KB)
  #define STAGE(KCN, BUF) do {                                                  \
    char* lb = (char*)smem + (BUF) * 32768;                                     \
    const char* gh = (const char*)ehp + (size_t)(KCN) * 16384;                  \
    const char* gl = (const char*)elp + (size_t)(KCN) * 16384;                  \
    _Pragma("unroll")                                                           \
    for (int q = 0; q < 4; ++q) {                                               \
      __builtin_amdgcn_global_load_lds(                                         \
        (const __attribute__((address_space(1))) void*)(gh + q*4096 + t*16),    \
        (__attribute__((address_space(3))) void*)(lb + q*4096 + wbase),         \
        16, 0, 0);                                                              \
      __builtin_amdgcn_global_load_lds(                                         \
        (const __attribute__((address_space(1))) void*)(gl + q*4096 + t*16),    \
        (__attribute__((address_space(3))) void*)(lb + 16384 + q*4096 + wbase), \
        16, 0, 0);                                                              \
    }                                                                           \
  } while (0)

  STAGE(0, 0);
  __syncthreads();

  const int boff = hi * 512 + col * 16;
  for (int kc = 0; kc < 128; ++kc) {
    const int cur = kc & 1;
    if (kc + 1 < 128) STAGE(kc + 1, cur ^ 1);   // issue early; drained at barrier
    const char* bb = (const char*)smem + cur * 32768;

    f32x16 c0 = {}, c1 = {}, c2 = {}, c3 = {};
    #pragma unroll
    for (int s = 0; s < 16; ++s) {
      short8 bh = *(const short8*)(bb + s * 1024 + boff);
      short8 bl = *(const short8*)(bb + 16384 + s * 1024 + boff);
      c0 = __builtin_amdgcn_mfma_f32_32x32x16_bf16(ah0[s], bh, c0, 0, 0, 0);
      c1 = __builtin_amdgcn_mfma_f32_32x32x16_bf16(ah1[s], bh, c1, 0, 0, 0);
      c2 = __builtin_amdgcn_mfma_f32_32x32x16_bf16(al0[s], bh, c2, 0, 0, 0);
      c3 = __builtin_amdgcn_mfma_f32_32x32x16_bf16(al1[s], bh, c3, 0, 0, 0);
      c0 = __builtin_amdgcn_mfma_f32_32x32x16_bf16(ah0[s], bl, c0, 0, 0, 0);
      c1 = __builtin_amdgcn_mfma_f32_32x32x16_bf16(ah1[s], bl, c1, 0, 0, 0);
    }

    // branchless top-2 (kc ascending -> first-index tie-break within lane)
    const float ev = esq[kc * 32 + col];
    #pragma unroll
    for (int r = 0; r < 16; ++r) {
      float sc0 = fmaf(-2.0f, c0[r] + c2[r], ev);   // row-block 0
      bool lt0 = sc0 < m1[r];
      ic[r] = lt0 ? kc : ic[r];
      m2[r] = fminf(m2[r], fmaxf(m1[r], sc0));
      m1[r] = fminf(m1[r], sc0);
      float sc1 = fmaf(-2.0f, c1[r] + c3[r], ev);   // row-block 1
      bool lt1 = sc1 < m1[16 + r];
      ic[16 + r] = lt1 ? kc : ic[16 + r];
      m2[16 + r] = fminf(m2[16 + r], fmaxf(m1[16 + r], sc1));
      m1[16 + r] = fminf(m1[16 + r], sc1);
    }
    __syncthreads();   // drains vmcnt: next chunk's LDS writes landed
  }
  #undef STAGE

  // merge top-2 across the 32 lanes (codes of each chunk)
  #pragma unroll
  for (int rb = 0; rb < 2; ++rb) {
    #pragma unroll
    for (int r = 0; r < 16; ++r) {
      const int j = rb * 16 + r;
      float a1 = m1[j], a2 = m2[j];
      int cd = ic[j] * 32 + col;
      #pragma unroll
      for (int off = 1; off < 32; off <<= 1) {
        float b1 = __shfl_xor(a1, off);
        float b2 = __shfl_xor(a2, off);
        int   bc = __shfl_xor(cd, off);
        bool take = (b1 < a1) || (b1 == a1 && bc < cd);
        float nm2 = take ? fminf(a1, b2) : fminf(a2, b1);
        if (take) { a1 = b1; cd = bc; }
        a2 = nm2;
      }
      if (col == 0) {
        const int orow = rowbase + rb * 32 + (r & 3) + 8 * (r >> 2) + 4 * hi;
        idx_out[orow] = cd;
        if (a2 - a1 < TAU) {
          unsigned int p = atomicAdd(counter, 1u);
          flag[p] = orow;
        }
      }
    }
  }
}

// ---------------- fallback fp32 argmin (if ws too small) ----------------
__global__ __launch_bounds__(256, 2) void argmin_kernel(
    const float4* __restrict__ z4, const float4* __restrict__ cb4,
    const float* __restrict__ esq, int* __restrict__ idx_out,
    int* __restrict__ flag, unsigned int* __restrict__ counter) {
  __shared__ float zt[DB][RB];
  __shared__ float et[DB][KB];
  const int t  = threadIdx.x;
  const int tr = t >> 4;
  const int tc = t & 15;
  const int row0 = blockIdx.x * RB;

  float min1[8], min2[8]; int idx1[8];
  #pragma unroll
  for (int i = 0; i < 8; ++i) { min1[i] = FLT_MAX; min2[i] = FLT_MAX; idx1[i] = 0; }

  for (int kc = 0; kc < K_CB / KB; ++kc) {
    const int k0 = kc * KB;
    float acc[8][8];
    #pragma unroll
    for (int i = 0; i < 8; ++i)
      #pragma unroll
      for (int j = 0; j < 8; ++j) acc[i][j] = 0.0f;

    float esqv[8];
    #pragma unroll
    for (int j = 0; j < 8; ++j) esqv[j] = esq[k0 + tc*8 + j];

    for (int dt = 0; dt < D_DIM / DB; ++dt) {
      __syncthreads();
      #pragma unroll
      for (int m = 0; m < 4; ++m) {
        int u  = t + 256*m;
        int dq = u & 7;
        int r  = u >> 3;
        float4 v = z4[(size_t)(row0 + r)*(D_DIM/4) + dt*8 + dq];
        zt[dq*4+0][r] = v.x; zt[dq*4+1][r] = v.y; zt[dq*4+2][r] = v.z; zt[dq*4+3][r] = v.w;
        float4 wv = cb4[(size_t)(k0 + r)*(D_DIM/4) + dt*8 + dq];
        et[dq*4+0][r] = wv.x; et[dq*4+1][r] = wv.y; et[dq*4+2][r] = wv.z; et[dq*4+3][r] = wv.w;
      }
      __syncthreads();

      #pragma unroll 8
      for (int d = 0; d < DB; ++d) {
        float4 za = *(const float4*)&zt[d][tr*8];
        float4 zb = *(const float4*)&zt[d][tr*8+4];
        float4 ea = *(const float4*)&et[d][tc*8];
        float4 eb = *(const float4*)&et[d][tc*8+4];
        float zr[8] = {za.x, za.y, za.z, za.w, zb.x, zb.y, zb.z, zb.w};
        float ev[8] = {ea.x, ea.y, ea.z, ea.w, eb.x, eb.y, eb.z, eb.w};
        #pragma unroll
        for (int i = 0; i < 8; ++i)
          #pragma unroll
          for (int j = 0; j < 8; ++j)
            acc[i][j] += zr[i] * ev[j];
      }
    }

    #pragma unroll
    for (int j = 0; j < 8; ++j) {
      const int k = k0 + tc*8 + j;
      #pragma unroll
      for (int i = 0; i < 8; ++i) {
        float s = esqv[j] - 2.0f * acc[i][j];
        if (s < min1[i]) { min2[i] = min1[i]; min1[i] = s; idx1[i] = k; }
        else if (s < min2[i]) { min2[i] = s; }
      }
    }
  }

  #pragma unroll
  for (int i = 0; i < 8; ++i) {
    float m1 = min1[i], m2 = min2[i]; int id = idx1[i];
    #pragma unroll
    for (int off = 1; off < 16; off <<= 1) {
      float om1 = __shfl_xor(m1, off);
      float om2 = __shfl_xor(m2, off);
      int   oid = __shfl_xor(id, off);
      bool take = (om1 < m1) || (om1 == m1 && oid < id);
      float nm2 = take ? fminf(m1, om2) : fminf(m2, om1);
      if (take) { m1 = om1; id = oid; }
      m2 = nm2;
    }
    if (tc == 0) {
      int row = row0 + tr*8 + i;
      idx_out[row] = id;
      if (m2 - m1 < TAU) {
        unsigned int p = atomicAdd(counter, 1u);
        flag[p] = row;
      }
    }
  }
}

// ---------------- numpy-fp32-emulated re-score of ambiguous rows ----------------
__global__ __launch_bounds__(256) void refine_np_kernel(
    const float* __restrict__ z, const float* __restrict__ cb,
    const float* __restrict__ esq, int* __restrict__ idx_out,
    const int* __restrict__ flag, const unsigned int* __restrict__ counter) {
  __shared__ float zrow[RR][D_DIM];
  __shared__ float zsq[RR];
  __shared__ float rbest[256];
  __shared__ int   rbidx[256];
  const int t = threadIdx.x;
  const unsigned int cnt = *counter;
  const unsigned int ngroups = (cnt + RR - 1) / RR;

  for (unsigned int g = blockIdx.x; g < ngroups; g += gridDim.x) {
    __syncthreads();
    const int nr = (int)min((unsigned int)RR, cnt - g*RR);
    #pragma unroll
    for (int r = 0; r < RR; ++r) {
      int fi = (int)(g*RR) + ((r < nr) ? r : 0);
      int row = flag[fi];
      zrow[r][t] = z[(size_t)row * D_DIM + t];
    }
    __syncthreads();
    if (t < RR) zsq[t] = np_sumsq256(&zrow[t][0]);
    __syncthreads();

    float best[RR]; int bidx[RR];
    #pragma unroll
    for (int r = 0; r < RR; ++r) { best[r] = FLT_MAX; bidx[r] = 0x7fffffff; }

    for (int m = 0; m < K_CB / 256; ++m) {
      const int k = m*256 + t;
      const float4* e4 = (const float4*)(cb + (size_t)k * D_DIM);
      float acc[RR];
      #pragma unroll
      for (int r = 0; r < RR; ++r) acc[r] = 0.0f;
      for (int dq = 0; dq < D_DIM/4; ++dq) {
        float4 ev = e4[dq];
        #pragma unroll
        for (int r = 0; r < RR; ++r) {
          acc[r] = __fmaf_rn(zrow[r][dq*4+0], ev.x, acc[r]);
          acc[r] = __fmaf_rn(zrow[r][dq*4+1], ev.y, acc[r]);
          acc[r] = __fmaf_rn(zrow[r][dq*4+2], ev.z, acc[r]);
          acc[r] = __fmaf_rn(zrow[r][dq*4+3], ev.w, acc[r]);
        }
      }
      const float ek = esq[k];
      #pragma unroll
      for (int r = 0; r < RR; ++r) {
        float sc = np_score(zsq[r], ek, acc[r]);
        if (sc < best[r]) { best[r] = sc; bidx[r] = k; }
      }
    }

    for (int r = 0; r < RR; ++r) {
      __syncthreads();
      rbest[t] = best[r]; rbidx[t] = bidx[r];
      __syncthreads();
      for (int off = 128; off > 0; off >>= 1) {
        if (t < off) {
          float ob = rbest[t+off]; int oi = rbidx[t+off];
          if (ob < rbest[t] || (ob == rbest[t] && oi < rbidx[t])) {
            rbest[t] = ob; rbidx[t] = oi;
          }
        }
        __syncthreads();
      }
      if (t == 0 && r < nr) idx_out[flag[g*RR + r]] = rbidx[0];
    }
  }
}

// ---------------- gather + outputs + loss partials ----------------
__global__ __launch_bounds__(256) void output_kernel(
    const float4* __restrict__ z4, const float4* __restrict__ cb4,
    const int* __restrict__ idx_out, float* __restrict__ out,
    double* __restrict__ partials) {
  const int g  = blockIdx.x * 256 + threadIdx.x;
  const int n  = g >> 6;
  const int dq = g & 63;
  const int id = idx_out[n];
  float4 q  = cb4[(size_t)id * (D_DIM/4) + dq];
  float4 zv = z4[(size_t)n  * (D_DIM/4) + dq];
  float dx = q.x - zv.x, dy = q.y - zv.y, dz = q.z - zv.z, dw = q.w - zv.w;
  double psum = (double)dx*dx + (double)dy*dy + (double)dz*dz + (double)dw*dw;
  size_t base = 1 + (size_t)n * D_DIM + (size_t)dq * 4;
  out[base+0] = q.x; out[base+1] = q.y; out[base+2] = q.z; out[base+3] = q.w;
  if (dq == 0) out[1 + (size_t)N_ROWS*D_DIM + n] = (float)id;

  __shared__ double sred[256];
  sred[threadIdx.x] = psum;
  __syncthreads();
  for (int off = 128; off > 0; off >>= 1) {
    if (threadIdx.x < off) sred[threadIdx.x] += sred[threadIdx.x + off];
    __syncthreads();
  }
  if (threadIdx.x == 0) partials[blockIdx.x] = sred[0];
}

__global__ __launch_bounds__(256) void loss_kernel(const double* __restrict__ partials,
                                                   float* __restrict__ out) {
  const int t = threadIdx.x;
  double s = 0.0;
  for (int m = 0; m < NUM_OUT_BLOCKS/256; ++m) s += partials[t + 256*m];
  __shared__ double sred[256];
  sred[t] = s;
  __syncthreads();
  for (int off = 128; off > 0; off >>= 1) {
    if (t < off) sred[t] += sred[t + off];
    __syncthreads();
  }
  if (t == 0) out[0] = (float)(1.25 * sred[0] / ((double)N_ROWS * (double)D_DIM));
}

extern "C" void kernel_launch(void* const* d_in, const int* in_sizes, int n_in,
                              void* d_out, int out_size, void* d_ws, size_t ws_size,
                              hipStream_t stream) {
  const float* z  = (const float*)d_in[0];
  const float* cb = (const float*)d_in[1];
  float* out = (float*)d_out;
  char* ws = (char*)d_ws;

  unsigned int* counter = (unsigned int*)(ws + WS_COUNTER);
  float*  esq      = (float*) (ws + WS_ESQ);
  int*    idx      = (int*)   (ws + WS_IDX);
  int*    flag     = (int*)   (ws + WS_FLAG);
  double* partials = (double*)(ws + WS_PART);

  (void)hipMemsetAsync(ws, 0, 16, stream);
  esq_np_kernel<<<K_CB/256, 256, 0, stream>>>(cb, esq);

  if (ws_size >= WS_NEEDED) {
    u16* ehp = (u16*)(ws + WS_EH);
    u16* elp = (u16*)(ws + WS_EL);
    esplit_perm_kernel<<<(K_CB*(D_DIM/8))/256, 256, 0, stream>>>(cb, ehp, elp);
    mfma_argmin32_kernel<<<N_ROWS/256, 256, 0, stream>>>(z, ehp, elp, esq,
                                                         idx, flag, counter);
  } else {
    argmin_kernel<<<N_ROWS/RB, 256, 0, stream>>>((const float4*)z, (const float4*)cb,
                                                 esq, idx, flag, counter);
  }

  refine_np_kernel<<<256, 256, 0, stream>>>(z, cb, esq, idx, flag, counter);
  output_kernel<<<NUM_OUT_BLOCKS, 256, 0, stream>>>((const float4*)z, (const float4*)cb,
                                                    idx, out, partials);
  loss_kernel<<<1, 256, 0, stream>>>(partials, out);
}

// Round 12
// 538.256 us; speedup vs baseline: 1.1549x; 1.1549x over previous
//
#include <hip/hip_runtime.h>
#include <float.h>

typedef __attribute__((ext_vector_type(8))) short short8;
typedef __attribute__((ext_vector_type(4))) float f32x4;
typedef unsigned short u16;
typedef unsigned int u32;

#define N_ROWS 65536
#define K_CB   4096
#define D_DIM  256
#define TAU    1.0e-3f
#define RR     8

// old-path tile params (fallback)
#define RB 128
#define KB 128
#define DB 32

// workspace layout (bytes)
#define WS_COUNTER 0
#define WS_ESQ     16
#define WS_IDX     (WS_ESQ + K_CB*4)
#define WS_FLAG    (WS_IDX + N_ROWS*4)
#define WS_PART    (WS_FLAG + N_ROWS*4)
#define NUM_OUT_BLOCKS ((N_ROWS*(D_DIM/4))/256)   // 16384
#define WS_EH      (WS_PART + NUM_OUT_BLOCKS*8)
#define WS_EL      (WS_EH + K_CB*D_DIM*2)
#define WS_NEEDED  (WS_EL + (size_t)K_CB*D_DIM*2)

// ---------- bf16 split helpers (RNE) ----------
__device__ __forceinline__ u16 f2bf(float x) {
  unsigned int u = __float_as_uint(x);
  unsigned int r = (u + 0x7fffu + ((u >> 16) & 1u)) >> 16;
  return (u16)r;
}
__device__ __forceinline__ float bf2f(u16 b) {
  return __uint_as_float((unsigned int)b << 16);
}
// np-exact final combine: fl( fl(zsq+esq) - fl(2*dot) )
__device__ __forceinline__ float np_score(float zsq, float ek, float dot) {
#pragma clang fp contract(off)
  float t1 = zsq + ek;
  float t2 = 2.0f * dot;
  return t1 - t2;
}

// ---------- numpy-emulated pairwise sum of squares ----------
__device__ __forceinline__ float np_sum128_sq(const float* p) {
#pragma clang fp contract(off)
  float r0 = p[0]*p[0], r1 = p[1]*p[1], r2 = p[2]*p[2], r3 = p[3]*p[3];
  float r4 = p[4]*p[4], r5 = p[5]*p[5], r6 = p[6]*p[6], r7 = p[7]*p[7];
  for (int i = 8; i < 128; i += 8) {
    r0 += p[i+0]*p[i+0]; r1 += p[i+1]*p[i+1];
    r2 += p[i+2]*p[i+2]; r3 += p[i+3]*p[i+3];
    r4 += p[i+4]*p[i+4]; r5 += p[i+5]*p[i+5];
    r6 += p[i+6]*p[i+6]; r7 += p[i+7]*p[i+7];
  }
  return ((r0+r1)+(r2+r3))+((r4+r5)+(r6+r7));
}
__device__ __forceinline__ float np_sumsq256(const float* p) {
#pragma clang fp contract(off)
  float a = np_sum128_sq(p);
  float b = np_sum128_sq(p + 128);
  return a + b;
}

__global__ __launch_bounds__(256) void esq_np_kernel(const float* __restrict__ cb,
                                                     float* __restrict__ esq) {
  const int k = blockIdx.x * 256 + threadIdx.x;
  esq[k] = np_sumsq256(cb + (size_t)k * D_DIM);
}

// ---------- codebook split hi/lo, codes-as-A MFMA layout (R6-validated) ----------
// Element offset within chunk c (8192 elems = 16 KB):
//   off = s*1024 + lq*256 + code*8 + j   (s = d>>5, lq = (d>>3)&3, code = k&31, j = d&7)
// A-frag read (k-step s, sub): lane l reads 16B at s*2048 + lq_lane*512 + sub*256
//   + (l&15)*16 — code = sub*16 + (l&15), k = (l>>4)*8 + j. [R6 PASS-validated]
__global__ __launch_bounds__(256) void esplit_ca_kernel(const float* __restrict__ cb,
                                                        u16* __restrict__ ehp,
                                                        u16* __restrict__ elp) {
  const int g  = blockIdx.x * 256 + threadIdx.x;   // k*32 + d8
  const int k  = g >> 5, d8 = g & 31;
  const int c  = k >> 5, code = k & 31;
  const int s  = d8 >> 2, lq = d8 & 3;
  const float* src = cb + (size_t)k * D_DIM + d8 * 8;
  float4 f0 = *(const float4*)src;
  float4 f1 = *(const float4*)(src + 4);
  float f[8] = {f0.x,f0.y,f0.z,f0.w,f1.x,f1.y,f1.z,f1.w};
  short8 h, lo;
  #pragma unroll
  for (int j = 0; j < 8; ++j) {
    u16 hb = f2bf(f[j]);
    h[j]  = (short)hb;
    lo[j] = (short)f2bf(f[j] - bf2f(hb));
  }
  const size_t off = (size_t)c*8192 + s*1024 + lq*256 + code*8;
  *(short8*)(ehp + off) = h;
  *(short8*)(elp + off) = lo;
}

// ---------------- codes-as-A 3-term split-bf16 MFMA argmin ----------------
// 256 thr = 4 waves, 2 blocks/CU. Wave owns 32 z-rows persistent as the MFMA
// B-operand (bzh/bzl = 128 VGPR). Codes stream as A from LDS (32 ds_read_b128
// -> 96 MFMAs per chunk). Key property: D[code][row] puts all scores of a row
// in ONE lane -> top-2 state is 6 regs (vs 96 rows-as-A) -> no spill.
// Staging via global_load_lds (no staging VGPRs); 1 barrier/chunk.
__global__ __launch_bounds__(256, 2) void coarse_ca_kernel(
    const float* __restrict__ z, const u16* __restrict__ ehp,
    const u16* __restrict__ elp, const float* __restrict__ esq,
    int* __restrict__ idx_out, int* __restrict__ flag,
    u32* __restrict__ counter) {
  __shared__ u16 smem[2 * 16384];   // 64 KB: 2 bufs x (eh 16KB | el 16KB)
  const int t = threadIdx.x;
  const int w = t >> 6, l = t & 63;
  const int l16 = l & 15, lq = l >> 4;
  const int rowbase = blockIdx.x * 128 + w * 32;
  const int wbase = w * 1024;   // wave-uniform LDS byte base for staging

  // B operand: z rows split hi/lo. row = rowbase + rs*16 + l16; k = lq*8+j,
  // frag s covers d = s*32 .. s*32+31. [R6-validated addressing]
  short8 bzh[2][8], bzl[2][8];
  #pragma unroll
  for (int rs = 0; rs < 2; ++rs) {
    const float* zp = z + (size_t)(rowbase + rs*16 + l16) * D_DIM + lq*8;
    #pragma unroll
    for (int s = 0; s < 8; ++s) {
      float4 f0 = *(const float4*)(zp + s*32);
      float4 f1 = *(const float4*)(zp + s*32 + 4);
      float f[8] = {f0.x,f0.y,f0.z,f0.w,f1.x,f1.y,f1.z,f1.w};
      short8 h, lo;
      #pragma unroll
      for (int j = 0; j < 8; ++j) {
        u16 hb = f2bf(f[j]);
        h[j]  = (short)hb;
        lo[j] = (short)f2bf(f[j] - bf2f(hb));
      }
      bzh[rs][s] = h; bzl[rs][s] = lo;
    }
  }

  float m1[2] = {FLT_MAX, FLT_MAX};
  float m2[2] = {FLT_MAX, FLT_MAX};
  int   ic[2] = {0, 0};

  // async global->LDS staging of one chunk (eh 16KB + el 16KB)
  #define STAGE(KCN, BUF) do {                                                  \
    char* lb = (char*)smem + (BUF) * 32768;                                     \
    const char* gh = (const char*)ehp + (size_t)(KCN) * 16384;                  \
    const char* gl = (const char*)elp + (size_t)(KCN) * 16384;                  \
    _Pragma("unroll")                                                           \
    for (int q = 0; q < 4; ++q) {                                               \
      __builtin_amdgcn_global_load_lds(                                         \
        (const __attribute__((address_space(1))) void*)(gh + q*4096 + t*16),    \
        (__attribute__((address_space(3))) void*)(lb + q*4096 + wbase),         \
        16, 0, 0);                                                              \
      __builtin_amdgcn_global_load_lds(                                         \
        (const __attribute__((address_space(1))) void*)(gl + q*4096 + t*16),    \
        (__attribute__((address_space(3))) void*)(lb + 16384 + q*4096 + wbase), \
        16, 0, 0);                                                              \
    }                                                                           \
  } while (0)

  STAGE(0, 0);
  __syncthreads();

  #define MFMA16(A, B, C) __builtin_amdgcn_mfma_f32_16x16x32_bf16(A, B, C, 0, 0, 0)
  #define TOP2(RS, SC, CODE) do {                                               \
    bool lt_ = (SC) < m1[RS];                                                   \
    m2[RS] = fminf(m2[RS], fmaxf(m1[RS], (SC)));                                \
    ic[RS] = lt_ ? (CODE) : ic[RS];                                             \
    m1[RS] = fminf(m1[RS], (SC));                                               \
  } while (0)

  for (int cc = 0; cc < 128; ++cc) {
    const int cur = cc & 1;
    if (cc + 1 < 128) STAGE(cc + 1, cur ^ 1);   // issue early; drained at barrier
    const char* bb = (const char*)smem + cur * 32768;
    float4 e0 = *(const float4*)(esq + cc*32 + lq*4);        // sub0 codes
    float4 e1 = *(const float4*)(esq + cc*32 + 16 + lq*4);   // sub1 codes

    f32x4 a00 = {}, a01 = {}, a10 = {}, a11 = {};   // [sub][rs]
    #pragma unroll
    for (int s = 0; s < 8; ++s) {
      const int ao = s*2048 + lq*512 + l16*16;
      short8 ah0 = *(const short8*)(bb + ao);
      short8 ah1 = *(const short8*)(bb + ao + 256);
      short8 al0 = *(const short8*)(bb + 16384 + ao);
      short8 al1 = *(const short8*)(bb + 16384 + ao + 256);
      // 12 MFMAs, 4 independent chains, same-chain gap = 4
      a00 = MFMA16(ah0, bzh[0][s], a00);
      a01 = MFMA16(ah0, bzh[1][s], a01);
      a10 = MFMA16(ah1, bzh[0][s], a10);
      a11 = MFMA16(ah1, bzh[1][s], a11);
      a00 = MFMA16(ah0, bzl[0][s], a00);
      a01 = MFMA16(ah0, bzl[1][s], a01);
      a10 = MFMA16(ah1, bzl[0][s], a10);
      a11 = MFMA16(ah1, bzl[1][s], a11);
      a00 = MFMA16(al0, bzh[0][s], a00);
      a01 = MFMA16(al0, bzh[1][s], a01);
      a10 = MFMA16(al1, bzh[0][s], a10);
      a11 = MFMA16(al1, bzh[1][s], a11);
    }

    // top-2 update, codes scanned ascending (sub0 then sub1) for tie-break.
    // lane's codes: sub*16 + lq*4 + r, for row rowbase + rs*16 + l16.
    #pragma unroll
    for (int r = 0; r < 4; ++r) {
      const float ev = ((const float*)&e0)[r];
      const int code = cc*32 + lq*4 + r;
      float s0 = fmaf(-2.0f, a00[r], ev);
      TOP2(0, s0, code);
      float s1 = fmaf(-2.0f, a01[r], ev);
      TOP2(1, s1, code);
    }
    #pragma unroll
    for (int r = 0; r < 4; ++r) {
      const float ev = ((const float*)&e1)[r];
      const int code = cc*32 + 16 + lq*4 + r;
      float s0 = fmaf(-2.0f, a10[r], ev);
      TOP2(0, s0, code);
      float s1 = fmaf(-2.0f, a11[r], ev);
      TOP2(1, s1, code);
    }
    __syncthreads();   // drains vmcnt: next chunk's LDS writes landed
  }
  #undef STAGE
  #undef MFMA16
  #undef TOP2

  // merge top-2 across the 4 lq-lanes of each row (xor 16, 32)
  #pragma unroll
  for (int rs = 0; rs < 2; ++rs) {
    float a1 = m1[rs], a2 = m2[rs]; int cd = ic[rs];
    #pragma unroll
    for (int off = 16; off < 64; off <<= 1) {
      float b1 = __shfl_xor(a1, off);
      float b2 = __shfl_xor(a2, off);
      int   bc = __shfl_xor(cd, off);
      bool take = (b1 < a1) || (b1 == a1 && bc < cd);
      float nm2 = take ? fminf(a1, b2) : fminf(a2, b1);
      if (take) { a1 = b1; cd = bc; }
      a2 = nm2;
    }
    if (lq == 0) {
      const int row = rowbase + rs*16 + l16;
      idx_out[row] = cd;
      if (a2 - a1 < TAU) {
        u32 p = atomicAdd(counter, 1u);
        flag[p] = row;
      }
    }
  }
}

// ---------------- fallback fp32 argmin (if ws too small) ----------------
__global__ __launch_bounds__(256, 2) void argmin_kernel(
    const float4* __restrict__ z4, const float4* __restrict__ cb4,
    const float* __restrict__ esq, int* __restrict__ idx_out,
    int* __restrict__ flag, unsigned int* __restrict__ counter) {
  __shared__ float zt[DB][RB];
  __shared__ float et[DB][KB];
  const int t  = threadIdx.x;
  const int tr = t >> 4;
  const int tc = t & 15;
  const int row0 = blockIdx.x * RB;

  float min1[8], min2[8]; int idx1[8];
  #pragma unroll
  for (int i = 0; i < 8; ++i) { min1[i] = FLT_MAX; min2[i] = FLT_MAX; idx1[i] = 0; }

  for (int kc = 0; kc < K_CB / KB; ++kc) {
    const int k0 = kc * KB;
    float acc[8][8];
    #pragma unroll
    for (int i = 0; i < 8; ++i)
      #pragma unroll
      for (int j = 0; j < 8; ++j) acc[i][j] = 0.0f;

    float esqv[8];
    #pragma unroll
    for (int j = 0; j < 8; ++j) esqv[j] = esq[k0 + tc*8 + j];

    for (int dt = 0; dt < D_DIM / DB; ++dt) {
      __syncthreads();
      #pragma unroll
      for (int m = 0; m < 4; ++m) {
        int u  = t + 256*m;
        int dq = u & 7;
        int r  = u >> 3;
        float4 v = z4[(size_t)(row0 + r)*(D_DIM/4) + dt*8 + dq];
        zt[dq*4+0][r] = v.x; zt[dq*4+1][r] = v.y; zt[dq*4+2][r] = v.z; zt[dq*4+3][r] = v.w;
        float4 wv = cb4[(size_t)(k0 + r)*(D_DIM/4) + dt*8 + dq];
        et[dq*4+0][r] = wv.x; et[dq*4+1][r] = wv.y; et[dq*4+2][r] = wv.z; et[dq*4+3][r] = wv.w;
      }
      __syncthreads();

      #pragma unroll 8
      for (int d = 0; d < DB; ++d) {
        float4 za = *(const float4*)&zt[d][tr*8];
        float4 zb = *(const float4*)&zt[d][tr*8+4];
        float4 ea = *(const float4*)&et[d][tc*8];
        float4 eb = *(const float4*)&et[d][tc*8+4];
        float zr[8] = {za.x, za.y, za.z, za.w, zb.x, zb.y, zb.z, zb.w};
        float ev[8] = {ea.x, ea.y, ea.z, ea.w, eb.x, eb.y, eb.z, eb.w};
        #pragma unroll
        for (int i = 0; i < 8; ++i)
          #pragma unroll
          for (int j = 0; j < 8; ++j)
            acc[i][j] += zr[i] * ev[j];
      }
    }

    #pragma unroll
    for (int j = 0; j < 8; ++j) {
      const int k = k0 + tc*8 + j;
      #pragma unroll
      for (int i = 0; i < 8; ++i) {
        float s = esqv[j] - 2.0f * acc[i][j];
        if (s < min1[i]) { min2[i] = min1[i]; min1[i] = s; idx1[i] = k; }
        else if (s < min2[i]) { min2[i] = s; }
      }
    }
  }

  #pragma unroll
  for (int i = 0; i < 8; ++i) {
    float m1 = min1[i], m2 = min2[i]; int id = idx1[i];
    #pragma unroll
    for (int off = 1; off < 16; off <<= 1) {
      float om1 = __shfl_xor(m1, off);
      float om2 = __shfl_xor(m2, off);
      int   oid = __shfl_xor(id, off);
      bool take = (om1 < m1) || (om1 == m1 && oid < id);
      float nm2 = take ? fminf(m1, om2) : fminf(m2, om1);
      if (take) { m1 = om1; id = oid; }
      m2 = nm2;
    }
    if (tc == 0) {
      int row = row0 + tr*8 + i;
      idx_out[row] = id;
      if (m2 - m1 < TAU) {
        unsigned int p = atomicAdd(counter, 1u);
        flag[p] = row;
      }
    }
  }
}

// ---------------- numpy-fp32-emulated re-score of ambiguous rows ----------------
__global__ __launch_bounds__(256) void refine_np_kernel(
    const float* __restrict__ z, const float* __restrict__ cb,
    const float* __restrict__ esq, int* __restrict__ idx_out,
    const int* __restrict__ flag, const unsigned int* __restrict__ counter) {
  __shared__ float zrow[RR][D_DIM];
  __shared__ float zsq[RR];
  __shared__ float rbest[256];
  __shared__ int   rbidx[256];
  const int t = threadIdx.x;
  const unsigned int cnt = *counter;
  const unsigned int ngroups = (cnt + RR - 1) / RR;

  for (unsigned int g = blockIdx.x; g < ngroups; g += gridDim.x) {
    __syncthreads();
    const int nr = (int)min((unsigned int)RR, cnt - g*RR);
    #pragma unroll
    for (int r = 0; r < RR; ++r) {
      int fi = (int)(g*RR) + ((r < nr) ? r : 0);
      int row = flag[fi];
      zrow[r][t] = z[(size_t)row * D_DIM + t];
    }
    __syncthreads();
    if (t < RR) zsq[t] = np_sumsq256(&zrow[t][0]);
    __syncthreads();

    float best[RR]; int bidx[RR];
    #pragma unroll
    for (int r = 0; r < RR; ++r) { best[r] = FLT_MAX; bidx[r] = 0x7fffffff; }

    for (int m = 0; m < K_CB / 256; ++m) {
      const int k = m*256 + t;
      const float4* e4 = (const float4*)(cb + (size_t)k * D_DIM);
      float acc[RR];
      #pragma unroll
      for (int r = 0; r < RR; ++r) acc[r] = 0.0f;
      for (int dq = 0; dq < D_DIM/4; ++dq) {
        float4 ev = e4[dq];
        #pragma unroll
        for (int r = 0; r < RR; ++r) {
          acc[r] = __fmaf_rn(zrow[r][dq*4+0], ev.x, acc[r]);
          acc[r] = __fmaf_rn(zrow[r][dq*4+1], ev.y, acc[r]);
          acc[r] = __fmaf_rn(zrow[r][dq*4+2], ev.z, acc[r]);
          acc[r] = __fmaf_rn(zrow[r][dq*4+3], ev.w, acc[r]);
        }
      }
      const float ek = esq[k];
      #pragma unroll
      for (int r = 0; r < RR; ++r) {
        float sc = np_score(zsq[r], ek, acc[r]);
        if (sc < best[r]) { best[r] = sc; bidx[r] = k; }
      }
    }

    for (int r = 0; r < RR; ++r) {
      __syncthreads();
      rbest[t] = best[r]; rbidx[t] = bidx[r];
      __syncthreads();
      for (int off = 128; off > 0; off >>= 1) {
        if (t < off) {
          float ob = rbest[t+off]; int oi = rbidx[t+off];
          if (ob < rbest[t] || (ob == rbest[t] && oi < rbidx[t])) {
            rbest[t] = ob; rbidx[t] = oi;
          }
        }
        __syncthreads();
      }
      if (t == 0 && r < nr) idx_out[flag[g*RR + r]] = rbidx[0];
    }
  }
}

// ---------------- gather + outputs + loss partials ----------------
__global__ __launch_bounds__(256) void output_kernel(
    const float4* __restrict__ z4, const float4* __restrict__ cb4,
    const int* __restrict__ idx_out, float* __restrict__ out,
    double* __restrict__ partials) {
  const int g  = blockIdx.x * 256 + threadIdx.x;
  const int n  = g >> 6;
  const int dq = g & 63;
  const int id = idx_out[n];
  float4 q  = cb4[(size_t)id * (D_DIM/4) + dq];
  float4 zv = z4[(size_t)n  * (D_DIM/4) + dq];
  float dx = q.x - zv.x, dy = q.y - zv.y, dz = q.z - zv.z, dw = q.w - zv.w;
  double psum = (double)dx*dx + (double)dy*dy + (double)dz*dz + (double)dw*dw;
  size_t base = 1 + (size_t)n * D_DIM + (size_t)dq * 4;
  out[base+0] = q.x; out[base+1] = q.y; out[base+2] = q.z; out[base+3] = q.w;
  if (dq == 0) out[1 + (size_t)N_ROWS*D_DIM + n] = (float)id;

  __shared__ double sred[256];
  sred[threadIdx.x] = psum;
  __syncthreads();
  for (int off = 128; off > 0; off >>= 1) {
    if (threadIdx.x < off) sred[threadIdx.x] += sred[threadIdx.x + off];
    __syncthreads();
  }
  if (threadIdx.x == 0) partials[blockIdx.x] = sred[0];
}

__global__ __launch_bounds__(256) void loss_kernel(const double* __restrict__ partials,
                                                   float* __restrict__ out) {
  const int t = threadIdx.x;
  double s = 0.0;
  for (int m = 0; m < NUM_OUT_BLOCKS/256; ++m) s += partials[t + 256*m];
  __shared__ double sred[256];
  sred[t] = s;
  __syncthreads();
  for (int off = 128; off > 0; off >>= 1) {
    if (t < off) sred[t] += sred[t + off];
    __syncthreads();
  }
  if (t == 0) out[0] = (float)(1.25 * sred[0] / ((double)N_ROWS * (double)D_DIM));
}

extern "C" void kernel_launch(void* const* d_in, const int* in_sizes, int n_in,
                              void* d_out, int out_size, void* d_ws, size_t ws_size,
                              hipStream_t stream) {
  const float* z  = (const float*)d_in[0];
  const float* cb = (const float*)d_in[1];
  float* out = (float*)d_out;
  char* ws = (char*)d_ws;

  unsigned int* counter = (unsigned int*)(ws + WS_COUNTER);
  float*  esq      = (float*) (ws + WS_ESQ);
  int*    idx      = (int*)   (ws + WS_IDX);
  int*    flag     = (int*)   (ws + WS_FLAG);
  double* partials = (double*)(ws + WS_PART);

  (void)hipMemsetAsync(ws, 0, 16, stream);
  esq_np_kernel<<<K_CB/256, 256, 0, stream>>>(cb, esq);

  if (ws_size >= WS_NEEDED) {
    u16* ehp = (u16*)(ws + WS_EH);
    u16* elp = (u16*)(ws + WS_EL);
    esplit_ca_kernel<<<(K_CB*(D_DIM/8))/256, 256, 0, stream>>>(cb, ehp, elp);
    coarse_ca_kernel<<<N_ROWS/128, 256, 0, stream>>>(z, ehp, elp, esq,
                                                     idx, flag, counter);
  } else {
    argmin_kernel<<<N_ROWS/RB, 256, 0, stream>>>((const float4*)z, (const float4*)cb,
                                                 esq, idx, flag, counter);
  }

  refine_np_kernel<<<256, 256, 0, stream>>>(z, cb, esq, idx, flag, counter);
  output_kernel<<<NUM_OUT_BLOCKS, 256, 0, stream>>>((const float4*)z, (const float4*)cb,
                                                    idx, out, partials);
  loss_kernel<<<1, 256, 0, stream>>>(partials, out);
}